// Round 1
// 708.244 us; speedup vs baseline: 1.0605x; 1.0605x over previous
//
#include <hip/hip_runtime.h>

#define D_   32
#define H_   256
#define W_   256
#define HW_  (H_ * W_)
#define DHW_ (D_ * H_ * W_)   // 2097152
#define V_   40000
#define CIN  16
#define COUT 32
#define P_   32
#define EPS_ 1e-5f

#define TD 2
#define TH 8
#define TW 32
#define NTX (W_ / TW)          // 8
#define NTY (H_ / TH)          // 32
#define NTZ (D_ / TD)          // 16
#define NT  (NTX * NTY * NTZ)  // 4096 tiles
#define TPOS (TD * TH * TW)    // 512
#define OH 16                  // channels per block (half of COUT)
#define TAP_CAP 768            // expected ~257, sigma ~73 (clustered) -> +7 sigma
#define TCT 512                // threads per tile_conv block (8 waves)

// ---------- K1: count voxels per tile-bin ----------
__global__ void bin_count_kernel(const int* __restrict__ idxs, int* __restrict__ counts) {
    int v = blockIdx.x * 256 + threadIdx.x;
    if (v >= V_) return;
    int w = idxs[3 * v], h = idxs[3 * v + 1], d = idxs[3 * v + 2];
    if ((unsigned)w < W_ && (unsigned)h < H_ && (unsigned)d < D_) {
        int b = (d / TD) * NTY * NTX + (h / TH) * NTX + (w / TW);
        atomicAdd(&counts[b], 1);
    }
}

// ---------- K2: exclusive prefix over 4096 bins + weight transpose ----------
// wt4[((half*27+k)*4+jj)*16+oo] = float4{ conv_w[o][4jj+i][k] : i=0..3 }, o=half*16+oo
__global__ void scan_kernel(const int* __restrict__ counts, int* __restrict__ starts,
                            int* __restrict__ cursor, const float* __restrict__ conv_w,
                            float4* __restrict__ wt4) {
    __shared__ int part[256];
    int t = threadIdx.x;
    int base = t * 16;
    int s = 0;
    for (int j = 0; j < 16; ++j) s += counts[base + j];
    part[t] = s;
    __syncthreads();
    for (int off = 1; off < 256; off <<= 1) {
        int val = part[t];
        int add = (t >= off) ? part[t - off] : 0;
        __syncthreads();
        part[t] = val + add;
        __syncthreads();
    }
    int run = (t > 0) ? part[t - 1] : 0;
    for (int j = 0; j < 16; ++j) {
        starts[base + j] = run;
        cursor[base + j] = run;
        run += counts[base + j];
    }
    // weight transpose: 3456 float4
    for (int n = t; n < 2 * 27 * 4 * 16; n += 256) {
        int oo = n & 15;
        int jj = (n >> 4) & 3;
        int m  = n >> 6;            // half*27 + k
        int k  = m % 27;
        int half = m / 27;
        int o = half * 16 + oo;
        float4 wv;
        wv.x = conv_w[(o * CIN + 4 * jj + 0) * 27 + k];
        wv.y = conv_w[(o * CIN + 4 * jj + 1) * 27 + k];
        wv.z = conv_w[(o * CIN + 4 * jj + 2) * 27 + k];
        wv.w = conv_w[(o * CIN + 4 * jj + 3) * 27 + k];
        wt4[n] = wv;
    }
}

// ---------- K3: fill bins: packed pos + permutation ----------
__global__ void bin_fill_kernel(const int* __restrict__ idxs, int* __restrict__ cursor,
                                int* __restrict__ pos_packed, int* __restrict__ perm) {
    int v = blockIdx.x * 256 + threadIdx.x;
    if (v >= V_) return;
    int w = idxs[3 * v], h = idxs[3 * v + 1], d = idxs[3 * v + 2];
    if ((unsigned)w < W_ && (unsigned)h < H_ && (unsigned)d < D_) {
        int b = (d / TD) * NTY * NTX + (h / TH) * NTX + (w / TW);
        int p = atomicAdd(&cursor[b], 1);
        pos_packed[p] = (d << 16) | (h << 8) | w;
        perm[v] = p;
    }
}

// ---------- K4: feats (mean over P) written in bin order, float4 granularity ----------
__global__ void featpack_kernel(const float* __restrict__ vox, const int* __restrict__ idxs,
                                const int* __restrict__ perm, float4* __restrict__ feats4) {
    int idx = blockIdx.x * 256 + threadIdx.x;     // (v, chunk-of-4-channels)
    if (idx >= V_ * 4) return;
    int v = idx >> 2, q = idx & 3;
    int w = idxs[3 * v], h = idxs[3 * v + 1], d = idxs[3 * v + 2];
    if (!((unsigned)w < W_ && (unsigned)h < H_ && (unsigned)d < D_)) return;
    int slot = perm[v];
    const float* base = vox + ((size_t)v * CIN + 4 * q) * P_;
    float m[4];
#pragma unroll
    for (int c = 0; c < 4; ++c) {
        const float4* p = (const float4*)(base + c * P_);
        float s = 0.f;
#pragma unroll
        for (int j = 0; j < P_ / 4; ++j) {
            float4 t = p[j];
            s += t.x + t.y + t.z + t.w;
        }
        m[c] = s * (1.0f / (float)P_);
    }
    feats4[slot * 4 + q] = make_float4(m[0], m[1], m[2], m[3]);
}

// ---------- K5: tile conv -> pre-norm output + BN stats (single pass) ----------
// block = 512 = 16 channels x 32 slots; grid = (NT, 2 halves)
// LDS ~63.2 KB -> 2 blocks/CU; 512 thr = 8 waves -> 16 waves/CU = 4 waves/SIMD
__global__ void __launch_bounds__(TCT, 4) tile_conv_kernel(
    const float4* __restrict__ feats4, const float4* __restrict__ wt4,
    const int* __restrict__ starts, const int* __restrict__ counts,
    const int* __restrict__ pos_packed, float* __restrict__ stats,
    float* __restrict__ out)
{
    __shared__ float  tile[TPOS * 16];     // [pos][oo^(pos&15)] xor-swizzled
    __shared__ float4 wsm4[27 * 4 * 16];   // [(k*4+jj)*16+oo]
    __shared__ int    taps[TAP_CAP];
    __shared__ int    seg_off[28];         // exclusive offsets (+ total)
    __shared__ int    seg_gs[27];
    __shared__ float  wsum[8][16], wsq[8][16];
    __shared__ int    ntap;

    int t = threadIdx.x;
    int tile_id = blockIdx.x;
    int half = blockIdx.y;
    int tx = tile_id % NTX, ty = (tile_id / NTX) % NTY, tz = tile_id / (NTX * NTY);
    int w0 = tx * TW, h0 = ty * TH, d0 = tz * TD;
    int obase = half * OH;

    // phase A: zero tile, stage weights, fetch neighbor-bin segments
    for (int j = t; j < TPOS * 16 / 4; j += TCT) ((float4*)tile)[j] = make_float4(0, 0, 0, 0);
    for (int j = t; j < 27 * 4 * 16; j += TCT) wsm4[j] = wt4[half * (27 * 4 * 16) + j];

    int segc = 0;
    if (t < 27) {
        int dz = t / 9 - 1, dy = (t / 3) % 3 - 1, dx = t % 3 - 1;
        int nz = tz + dz, ny = ty + dy, nx = tx + dx;
        int gs = 0;
        if ((unsigned)nz < NTZ && (unsigned)ny < NTY && (unsigned)nx < NTX) {
            int b = nz * NTY * NTX + ny * NTX + nx;
            gs = starts[b];
            segc = counts[b];
        }
        seg_gs[t] = gs;
    }
    // wave-0 register scan over the 27 counts (replaces serial thread-0 prefix)
    if (t < 64) {
        int x = segc;            // lanes >= 27 contribute 0
        int c0 = x;
#pragma unroll
        for (int off = 1; off < 32; off <<= 1) {
            int y = __shfl_up(x, off);
            if (t >= off) x += y;
        }
        if (t < 27) seg_off[t] = x - c0;   // exclusive
        if (t == 26) seg_off[27] = x;      // total
    }
    if (t == 0) ntap = 0;
    __syncthreads();
    int ncand = seg_off[27];

    // phase B: tap generation (binary search + batched tap-slot reservation)
    for (int j = t; j < ncand; j += TCT) {
        int lo = 0, hi = 27;
#pragma unroll
        for (int it = 0; it < 5; ++it) {   // 27 -> 14 -> 7 -> 4 -> 2 -> 1
            int mid = (lo + hi) >> 1;
            if (seg_off[mid] <= j) lo = mid; else hi = mid;
        }
        int b = lo;
        int src = seg_gs[b] + (j - seg_off[b]);
        int pp = pos_packed[src];
        int vw = pp & 255, vh = (pp >> 8) & 255, vd = pp >> 16;
        int dlo = max(vd - 1, d0), dhi = min(vd + 1, d0 + TD - 1);
        int hlo = max(vh - 1, h0), hhi = min(vh + 1, h0 + TH - 1);
        int wlo = max(vw - 1, w0), whi = min(vw + 1, w0 + TW - 1);
        int nd = dhi - dlo + 1, nh = hhi - hlo + 1, nw = whi - wlo + 1;
        if (nd > 0 && nh > 0 && nw > 0) {
            int npos = nd * nh * nw;
            int bslot = atomicAdd(&ntap, npos);   // one atomic per contributing candidate
            int i = 0;
            for (int dq = dlo; dq <= dhi; ++dq)
                for (int hq = hlo; hq <= hhi; ++hq)
                    for (int wq = wlo; wq <= whi; ++wq) {
                        int k = ((vd - dq + 1) * 3 + (vh - hq + 1)) * 3 + (vw - wq + 1);
                        int pos = ((dq - d0) * TH + (hq - h0)) * TW + (wq - w0);
                        int s2 = bslot + i; ++i;
                        if (s2 < TAP_CAP) taps[s2] = (src << 14) | (k << 9) | pos;
                    }
        }
    }
    __syncthreads();
    int nt = min(ntap, TAP_CAP);

    // phase C: uniform scatter: each tap = 4 b128 LDS weight reads + 16 FMA + ds_add
    int oo = t & 15;
    int slot = t >> 4;                      // 32 slot groups
    for (int j = slot; j < nt; j += 32) {
        unsigned tap = (unsigned)taps[j];
        int pos = tap & 511;
        int k = (tap >> 9) & 31;
        int src = tap >> 14;
        const float4* fp = feats4 + src * 4;      // broadcast across 16 oo lanes
        float4 f0 = fp[0], f1 = fp[1], f2 = fp[2], f3 = fp[3];
        const float4* wp = &wsm4[(k * 4) * 16 + oo];
        float4 q0 = wp[0], q1 = wp[16], q2 = wp[32], q3 = wp[48];
        float acc = q0.x * f0.x + q0.y * f0.y + q0.z * f0.z + q0.w * f0.w
                  + q1.x * f1.x + q1.y * f1.y + q1.z * f1.z + q1.w * f1.w
                  + q2.x * f2.x + q2.y * f2.y + q2.z * f2.z + q2.w * f2.w
                  + q3.x * f3.x + q3.y * f3.y + q3.z * f3.z + q3.w * f3.w;
        atomicAdd(&tile[pos * 16 + (oo ^ (pos & 15))], acc);
    }
    __syncthreads();

    // phase D1: BN partial stats (bias cancels analytically)
    float s1 = 0.f, s2 = 0.f;
    for (int p = slot; p < TPOS; p += 32) {
        float sv = tile[p * 16 + (oo ^ (p & 15))];
        s1 += sv;
        s2 += sv * sv;
    }
    s1 += __shfl_xor(s1, 16); s2 += __shfl_xor(s2, 16);
    s1 += __shfl_xor(s1, 32); s2 += __shfl_xor(s2, 32);
    int wave = t >> 6, lane = t & 63;
    if (lane < 16) { wsum[wave][lane] = s1; wsq[wave][lane] = s2; }

    // phase D2: write pre-norm output, coalesced (conflict-free scalar LDS reads)
    int wl = t & 31;
    for (int r = t >> 5; r < OH * TD * TH; r += 16) {
        int oo2 = r >> 4;          // TD*TH = 16
        int rem = r & 15;
        int pos = rem * TW + wl;
        int dl = rem >> 3, hl = rem & 7;
        out[(size_t)(obase + oo2) * DHW_ + (size_t)(d0 + dl) * HW_ +
            (size_t)(h0 + hl) * W_ + (w0 + wl)] = tile[pos * 16 + (oo2 ^ (pos & 15))];
    }
    __syncthreads();
    if (t < 16) {
        float a = wsum[0][t] + wsum[1][t] + wsum[2][t] + wsum[3][t]
                + wsum[4][t] + wsum[5][t] + wsum[6][t] + wsum[7][t];
        float b = wsq[0][t] + wsq[1][t] + wsq[2][t] + wsq[3][t]
                + wsq[4][t] + wsq[5][t] + wsq[6][t] + wsq[7][t];
        atomicAdd(&stats[obase + t], a);
        atomicAdd(&stats[COUT + obase + t], b);
    }
}

// ---------- K6: finalize per-channel scale A and shift B ----------
__global__ void finalize_kernel(const float* __restrict__ stats,
                                const float* __restrict__ gamma,
                                const float* __restrict__ beta,
                                float* __restrict__ mi) {
    int t = threadIdx.x;
    if (t < COUT) {
        float n = (float)DHW_;
        float m1 = stats[t] / n;
        float m2 = stats[COUT + t] / n;
        float var = fmaxf(m2 - m1 * m1, 0.f);
        float inv = rsqrtf(var + EPS_);
        float A = gamma[t] * inv;
        mi[t] = A;
        mi[COUT + t] = -m1 * A + beta[t];
    }
}

// ---------- K7: in-place normalize + affine + ReLU (pure BW) ----------
__global__ void norm_kernel(float* __restrict__ out, const float* __restrict__ mi) {
    int idx4 = blockIdx.x * 256 + threadIdx.x;
    int c = idx4 >> 19;            // DHW_/4 = 2^19
    float A = mi[c], B = mi[COUT + c];
    float4 x = ((const float4*)out)[idx4];
    x.x = fmaxf(x.x * A + B, 0.f);
    x.y = fmaxf(x.y * A + B, 0.f);
    x.z = fmaxf(x.z * A + B, 0.f);
    x.w = fmaxf(x.w * A + B, 0.f);
    ((float4*)out)[idx4] = x;
}

extern "C" void kernel_launch(void* const* d_in, const int* in_sizes, int n_in,
                              void* d_out, int out_size, void* d_ws, size_t ws_size,
                              hipStream_t stream) {
    const float* voxels  = (const float*)d_in[0];
    const int*   indices = (const int*)  d_in[1];
    const float* conv_w  = (const float*)d_in[2];
    const float* gamma   = (const float*)d_in[4];
    const float* beta    = (const float*)d_in[5];
    float* out = (float*)d_out;

    float4* wt4     = (float4*)d_ws;                     // 3456 float4
    float4* feats4  = wt4 + 3456;                        // V*4 float4
    int*    counts  = (int*)(feats4 + (size_t)V_ * 4);   // NT
    int*    starts  = counts + NT;
    int*    cursor  = starts + NT;
    int*    pos_pk  = cursor + NT;                       // V
    int*    perm    = pos_pk + V_;                       // V
    float*  stats   = (float*)(perm + V_);               // 64
    float*  mi      = stats + 2 * COUT;                  // 64

    hipMemsetAsync(counts, 0, NT * sizeof(int), stream);
    hipMemsetAsync(stats, 0, 2 * COUT * sizeof(float), stream);

    bin_count_kernel<<<(V_ + 255) / 256, 256, 0, stream>>>(indices, counts);
    scan_kernel<<<1, 256, 0, stream>>>(counts, starts, cursor, conv_w, wt4);
    bin_fill_kernel<<<(V_ + 255) / 256, 256, 0, stream>>>(indices, cursor, pos_pk, perm);
    featpack_kernel<<<(V_ * 4 + 255) / 256, 256, 0, stream>>>(voxels, indices, perm, feats4);

    dim3 grid(NT, 2);
    tile_conv_kernel<<<grid, TCT, 0, stream>>>(feats4, wt4, starts, counts, pos_pk,
                                               stats, out);
    finalize_kernel<<<1, 64, 0, stream>>>(stats, gamma, beta, mi);

    const int n4 = COUT * DHW_ / 4;
    norm_kernel<<<n4 / 256, 256, 0, stream>>>(out, mi);
}